// Round 12
// baseline (895.257 us; speedup 1.0000x reference)
//
#include <hip/hip_runtime.h>
#include <math.h>

#define N_NODES 50000
#define M_PAD   50048   // 391 * 128
#define N_EDGES 800000
#define HID 512

typedef short bf16x8 __attribute__((ext_vector_type(8)));
typedef float f32x4  __attribute__((ext_vector_type(4)));
typedef unsigned short u16x4 __attribute__((ext_vector_type(4)));
typedef unsigned short u16x8 __attribute__((ext_vector_type(8)));

__device__ inline float b2f(unsigned short u) {
    union { unsigned int i; float f; } v; v.i = ((unsigned int)u) << 16; return v.f;
}
__device__ inline unsigned short f2b(float f) {
    union { float f; unsigned int i; } v; v.f = f;
    unsigned int r = v.i + 0x7FFFu + ((v.i >> 16) & 1u);
    return (unsigned short)(r >> 16);
}

// ---------------- CSR build ----------------

__global__ void zero_kernel(int* __restrict__ p, int n) {
    int i = blockIdx.x * blockDim.x + threadIdx.x;
    if (i < n) p[i] = 0;
}

__global__ void detect_kernel(const int* __restrict__ e, int* __restrict__ flag) {
    if (blockIdx.x == 0 && threadIdx.x == 0) {
        int is64 = 1;
        for (int i = 0; i < 16; ++i)
            if (e[2 * i + 1] != 0) is64 = 0;
        *flag = is64;
    }
}

__global__ void hist_kernel(const void* __restrict__ eidx, const int* __restrict__ flag,
                            int* __restrict__ counts) {
    int e = blockIdx.x * blockDim.x + threadIdx.x;
    if (e >= N_EDGES) return;
    int is64 = *flag;
    int d;
    if (is64) d = (int)((const long long*)eidx)[N_EDGES + e];
    else      d = ((const int*)eidx)[N_EDGES + e];
    atomicAdd(&counts[d], 1);
}

__global__ __launch_bounds__(1024) void scan_kernel(const int* __restrict__ counts,
                                                    int* __restrict__ offsets) {
    __shared__ int sums[1024];
    int t = threadIdx.x;
    const int CH = (N_NODES + 1023) / 1024;  // 49
    int lo = t * CH;
    int hi = min(lo + CH, N_NODES);
    int s = 0;
    for (int i = lo; i < hi; ++i) s += counts[i];
    sums[t] = s;
    __syncthreads();
    for (int off = 1; off < 1024; off <<= 1) {
        int v = 0;
        if (t >= off) v = sums[t - off];
        __syncthreads();
        sums[t] += v;
        __syncthreads();
    }
    int excl = (t == 0) ? 0 : sums[t - 1];
    for (int i = lo; i < hi; ++i) { offsets[i] = excl; excl += counts[i]; }
    if (t == 1023) offsets[N_NODES] = excl;
}

__global__ void fill_kernel(const void* __restrict__ eidx, const int* __restrict__ flag,
                            const int* __restrict__ offsets, int* __restrict__ cursor,
                            int* __restrict__ edge_src) {
    int e = blockIdx.x * blockDim.x + threadIdx.x;
    if (e >= N_EDGES) return;
    int is64 = *flag;
    int s, d;
    if (is64) {
        const long long* p = (const long long*)eidx;
        s = (int)p[e];
        d = (int)p[N_EDGES + e];
    } else {
        const int* p = (const int*)eidx;
        s = p[e];
        d = p[N_EDGES + e];
    }
    int pos = atomicAdd(&cursor[d], 1);
    edge_src[offsets[d] + pos] = s;
}

// ---------------- conversions ----------------

// x (f32 [N,256]) -> bf16 into feat-half of Cat1 ([M][512], cols 256..512)
__global__ __launch_bounds__(256) void xconv_kernel(const float* __restrict__ x,
                                                    unsigned short* __restrict__ cat1) {
    int id = blockIdx.x * 256 + threadIdx.x;
    if (id >= M_PAD * 64) return;
    int row = id >> 6;
    int c = (id & 63) * 4;
    float4 v = make_float4(0.f, 0.f, 0.f, 0.f);
    if (row < N_NODES) v = *(const float4*)(x + (size_t)row * 256 + c);
    ushort4 h;
    h.x = f2b(v.x); h.y = f2b(v.y); h.z = f2b(v.z); h.w = f2b(v.w);
    *(ushort4*)(cat1 + (size_t)row * 512 + 256 + c) = h;
}

// W (f32 [K,512]) -> transposed bf16 into Wcat[n][off + k], row stride ktot
__global__ __launch_bounds__(128) void wconv_kernel(const float* __restrict__ W,
                                                    unsigned short* __restrict__ T,
                                                    int K, int ktot, int off) {
    int n = blockIdx.x;  // 0..511
    for (int k = threadIdx.x; k < K; k += 128)
        T[(size_t)n * ktot + off + k] = f2b(W[(size_t)k * HID + n]);
}

// ---------------- aggregate: 64-col XCD-pinned slices, 4 edge-groups/wave ----------------
// NSLICE = W/64; slice = blockIdx.x % NSLICE -> XCD-pinned (R10: FETCH 372->190MB).
// Wave = (node, slice).  64 lanes = 4 edge-groups x 16 lanes; group g handles
// edge i+g, lane owns 4 cols (u16x4 8B load).  Per wave-iter = 4 edges, so
// iterations = NSLICE*deg/4 (R10's VALU-bound 6.4M iters -> 1.6M).  Group
// partials combined at the end with 2x shfl_xor; lanes 0-15 write.

template <int W>
__global__ __launch_bounds__(256) void aggregate_kernel(const unsigned short* __restrict__ Fh,
                                                        const int* __restrict__ off,
                                                        const int* __restrict__ esrc,
                                                        unsigned short* __restrict__ Ah) {
    const int NSLICE = W / 64;
    const int STRIDE = 2 * W;
    const int slice = blockIdx.x % NSLICE;
    const int chunk = blockIdx.x / NSLICE;
    const int wid = threadIdx.x >> 6;
    const int lane = threadIdx.x & 63;
    const int node = chunk * 4 + wid;
    if (node >= N_NODES) return;
    const int beg = off[node], end = off[node + 1];
    const int deg = end - beg;
    const int grp = lane >> 4;                      // 0..3: edge group
    const int col = slice * 64 + (lane & 15) * 4;   // 4 cols per lane
    const unsigned short* F = Fh + col;

    float a0 = 0.f, a1 = 0.f, a2 = 0.f, a3 = 0.f;
    int idxv = 0;
    for (int i = 0; i < deg; i += 4) {
        const int b = i & 63;
        if (b == 0) idxv = (beg + i + lane < end) ? esrc[beg + i + lane] : 0;
        const int s = __shfl(idxv, b + grp);        // per-lane source (bpermute)
        if (i + grp < deg) {
            u16x4 v = *(const u16x4*)(F + (size_t)s * STRIDE);
            a0 += b2f(v[0]); a1 += b2f(v[1]); a2 += b2f(v[2]); a3 += b2f(v[3]);
        }
    }
    // combine the 4 group partials (lanes l, l+16, l+32, l+48 share cols)
    a0 += __shfl_xor(a0, 16); a0 += __shfl_xor(a0, 32);
    a1 += __shfl_xor(a1, 16); a1 += __shfl_xor(a1, 32);
    a2 += __shfl_xor(a2, 16); a2 += __shfl_xor(a2, 32);
    a3 += __shfl_xor(a3, 16); a3 += __shfl_xor(a3, 32);
    if (lane < 16) {
        u16x4 h;
        h[0] = f2b(a0); h[1] = f2b(a1); h[2] = f2b(a2); h[3] = f2b(a3);
        *(u16x4*)(Ah + (size_t)node * STRIDE + col) = h;
    }
}

// ---------------- concat-K MFMA GEMM: 128x256 tile, 8 waves, 2-phase dbuf ----------------
// out = Acat @ Bcat^T + bias.  1D grid, bijective XCD-pair swizzle: the two
// bn-halves of the same 128-row A panel land adjacent on the SAME XCD.

template <int FINAL>
__global__ __launch_bounds__(512, 2) void gemm_mfma_kernel(
    const unsigned short* __restrict__ A, const unsigned short* __restrict__ B,
    const float* __restrict__ bias, float* __restrict__ outF,
    unsigned short* __restrict__ pre, int K) {
    __shared__ unsigned short S[2 * 12288];  // u16 elems: 2 x (4096 A + 8192 B)
    const int T = gridDim.x;          // 782
    const int q = T >> 3, r = T & 7;
    const int xcd = blockIdx.x & 7;
    const int n0 = blockIdx.x >> 3;
    const int g = xcd * q + min(xcd, r) + n0;
    const int bm = (g >> 1) * 128;
    const int bn = (g & 1) * 256;

    const int tid = threadIdx.x;
    const int l = tid & 63;
    const int w = tid >> 6;          // 0..7
    const int wr = (w >> 2) * 64;    // 2 row-waves
    const int wc = (w & 3) * 64;     // 4 col-waves

    const int se = (tid >> 2) * 32 + (tid & 3) * 8;
    const unsigned short* gA  = A + (size_t)(bm + (tid >> 2)) * K + (tid & 3) * 8;
    const unsigned short* gB0 = B + (size_t)(bn + (tid >> 2)) * K + (tid & 3) * 8;
    const unsigned short* gB1 = B + (size_t)(bn + 128 + (tid >> 2)) * K + (tid & 3) * 8;

    f32x4 acc[4][4];
#pragma unroll
    for (int m = 0; m < 4; ++m)
#pragma unroll
        for (int nn = 0; nn < 4; ++nn) acc[m][nn] = (f32x4){0.f, 0.f, 0.f, 0.f};

    const int aoff = (wr + (l & 15)) * 32 + (l >> 4) * 8;
    const int woff = 4096 + (wc + (l & 15)) * 32 + (l >> 4) * 8;
    const int ktiles = K >> 5;

    auto STAGE = [&](int buf, int kt) {
        unsigned short* lb = &S[buf * 12288];
        __builtin_amdgcn_global_load_lds(
            (const __attribute__((address_space(1))) void*)(gA + kt * 32),
            (__attribute__((address_space(3))) void*)(lb + se), 16, 0, 0);
        __builtin_amdgcn_global_load_lds(
            (const __attribute__((address_space(1))) void*)(gB0 + kt * 32),
            (__attribute__((address_space(3))) void*)(lb + 4096 + se), 16, 0, 0);
        __builtin_amdgcn_global_load_lds(
            (const __attribute__((address_space(1))) void*)(gB1 + kt * 32),
            (__attribute__((address_space(3))) void*)(lb + 8192 + se), 16, 0, 0);
    };

    STAGE(0, 0);
    __syncthreads();

    for (int kt = 0; kt < ktiles; ++kt) {
        if (kt + 1 < ktiles) STAGE((kt + 1) & 1, kt + 1);  // prefetch next
        const int sb = (kt & 1) * 12288;

        bf16x8 af[4], wf[4];
#pragma unroll
        for (int m = 0; m < 4; ++m)
            af[m] = *(const bf16x8*)&S[sb + aoff + m * 512];
#pragma unroll
        for (int nn = 0; nn < 4; ++nn)
            wf[nn] = *(const bf16x8*)&S[sb + woff + nn * 512];
#pragma unroll
        for (int m = 0; m < 4; ++m)
#pragma unroll
            for (int nn = 0; nn < 4; ++nn)
                acc[m][nn] = __builtin_amdgcn_mfma_f32_16x16x32_bf16(af[m], wf[nn], acc[m][nn], 0, 0, 0);
        __syncthreads();
    }

    const int r0 = bm + wr + (l >> 4) * 4;
    const int c0 = bn + wc + (l & 15);
#pragma unroll
    for (int nn = 0; nn < 4; ++nn) {
        const float bv = bias[c0 + nn * 16];
#pragma unroll
        for (int m = 0; m < 4; ++m) {
#pragma unroll
            for (int j = 0; j < 4; ++j) {
                int gr = r0 + m * 16 + j;
                if (gr < N_NODES) {
                    float val = acc[m][nn][j] + bv;
                    if constexpr (FINAL)
                        outF[(size_t)gr * HID + c0 + nn * 16] = val;
                    else
                        pre[(size_t)gr * HID + c0 + nn * 16] = f2b(val);
                }
            }
        }
    }
}

// ---------------- row L2-normalize + ELU (wave-per-row) ----------------

template <int FINAL>
__global__ __launch_bounds__(256) void norm_elu_kernel(const void* __restrict__ inp,
                                                       float* __restrict__ outF,
                                                       unsigned short* __restrict__ Fh) {
    const int wid = threadIdx.x >> 6;
    const int lane = threadIdx.x & 63;
    const int row = blockIdx.x * 4 + wid;
    if (row >= N_NODES) return;
    float r[8];
    if constexpr (FINAL) {
        const float* p = (const float*)inp + (size_t)row * HID + lane * 8;
        float4 v0 = *(const float4*)p;
        float4 v1 = *(const float4*)(p + 4);
        r[0] = v0.x; r[1] = v0.y; r[2] = v0.z; r[3] = v0.w;
        r[4] = v1.x; r[5] = v1.y; r[6] = v1.z; r[7] = v1.w;
    } else {
        const unsigned short* p = (const unsigned short*)inp + (size_t)row * HID + lane * 8;
        u16x8 v = *(const u16x8*)p;
#pragma unroll
        for (int j = 0; j < 8; ++j) r[j] = b2f(v[j]);
    }
    float ss = 0.f;
#pragma unroll
    for (int j = 0; j < 8; ++j) ss += r[j] * r[j];
#pragma unroll
    for (int o = 32; o > 0; o >>= 1) ss += __shfl_xor(ss, o);
    float inv = 1.f / fmaxf(sqrtf(ss), 1e-12f);
#pragma unroll
    for (int j = 0; j < 8; ++j) {
        r[j] *= inv;
        r[j] = r[j] > 0.f ? r[j] : expm1f(r[j]);
    }
    if constexpr (FINAL) {
        float* q = outF + (size_t)row * HID + lane * 8;
        *(float4*)q = make_float4(r[0], r[1], r[2], r[3]);
        *(float4*)(q + 4) = make_float4(r[4], r[5], r[6], r[7]);
    } else {
        unsigned short* q = Fh + (size_t)row * 1024 + lane * 8;
        u16x8 h;
#pragma unroll
        for (int j = 0; j < 8; ++j) h[j] = f2b(r[j]);
        *(u16x8*)q = h;
    }
}

// ---------------- launch ----------------

extern "C" void kernel_launch(void* const* d_in, const int* in_sizes, int n_in,
                              void* d_out, int out_size, void* d_ws, size_t ws_size,
                              hipStream_t stream) {
    const float* x    = (const float*)d_in[0];
    const void*  eidx = d_in[1];
    const float* Wl0 = (const float*)d_in[2];
    const float* bl0 = (const float*)d_in[3];
    const float* Wr0 = (const float*)d_in[4];
    const float* Wl1 = (const float*)d_in[5];
    const float* bl1 = (const float*)d_in[6];
    const float* Wr1 = (const float*)d_in[7];
    const float* Wl2 = (const float*)d_in[8];
    const float* bl2 = (const float*)d_in[9];
    const float* Wr2 = (const float*)d_in[10];
    float* outF = (float*)d_out;
    unsigned short* preB = (unsigned short*)d_out;  // bf16 preact scratch (layers 1-2)

    char* ws = (char*)d_ws;
    size_t o = 0;
    auto alloc = [&](size_t bytes) { void* p = ws + o; o += (bytes + 255) & ~(size_t)255; return p; };

    // Concat activation planes: Cat1 [M][512] (agg256|feat256), Cat2 [M][1024]
    unsigned short* Cat1 = (unsigned short*)alloc((size_t)M_PAD * 512 * 2);
    unsigned short* Cat2 = (unsigned short*)alloc((size_t)M_PAD * 1024 * 2);

    unsigned short* Wcat0 = (unsigned short*)alloc(512 * 512 * 2);
    unsigned short* Wcat1 = (unsigned short*)alloc(512 * 1024 * 2);
    unsigned short* Wcat2 = (unsigned short*)alloc(512 * 1024 * 2);

    // counts and cursor MUST be one contiguous block (R2/R3 lesson: 256B alloc
    // rounding left cursor tail poisoned -> OOB writes -> GPU fault).
    int* counts   = (int*)alloc((size_t)2 * N_NODES * 4);
    int* cursor   = counts + N_NODES;
    int* offsets  = (int*)alloc((size_t)(N_NODES + 1) * 4);
    int* edge_src = (int*)alloc((size_t)N_EDGES * 4);
    int* flag     = (int*)alloc(256);

    // ---- CSR build ----
    zero_kernel<<<(2 * N_NODES + 255) / 256, 256, 0, stream>>>(counts, 2 * N_NODES);
    detect_kernel<<<1, 64, 0, stream>>>((const int*)eidx, flag);
    hist_kernel<<<(N_EDGES + 255) / 256, 256, 0, stream>>>(eidx, flag, counts);
    scan_kernel<<<1, 1024, 0, stream>>>(counts, offsets);
    fill_kernel<<<(N_EDGES + 255) / 256, 256, 0, stream>>>(eidx, flag, offsets, cursor, edge_src);

    // ---- conversions ----
    xconv_kernel<<<(M_PAD * 64 + 255) / 256, 256, 0, stream>>>(x, Cat1);
    wconv_kernel<<<512, 128, 0, stream>>>(Wl0, Wcat0, 256, 512, 0);
    wconv_kernel<<<512, 128, 0, stream>>>(Wr0, Wcat0, 256, 512, 256);
    wconv_kernel<<<512, 128, 0, stream>>>(Wl1, Wcat1, 512, 1024, 0);
    wconv_kernel<<<512, 128, 0, stream>>>(Wr1, Wcat1, 512, 1024, 512);
    wconv_kernel<<<512, 128, 0, stream>>>(Wl2, Wcat2, 512, 1024, 0);
    wconv_kernel<<<512, 128, 0, stream>>>(Wr2, Wcat2, 512, 1024, 512);

    const int ggrid = 2 * (M_PAD / 128);   // 782, 1D (swizzle computes bm/bn)
    const int nchunk = (N_NODES + 3) / 4;  // 4 nodes (waves) per 256-block

    // layer 1 (feat 256): Cat1 = agg|x, K=512.  4 col-slices of 64.
    aggregate_kernel<256><<<nchunk * 4, 256, 0, stream>>>(Cat1 + 256, offsets, edge_src, Cat1);
    gemm_mfma_kernel<0><<<ggrid, 512, 0, stream>>>(Cat1, Wcat0, bl0, nullptr, preB, 512);
    norm_elu_kernel<0><<<nchunk, 256, 0, stream>>>(preB, nullptr, Cat2 + 512);

    // layer 2 (feat 512): Cat2 = agg|feat, K=1024.  8 col-slices of 64 (XCD-pinned).
    aggregate_kernel<512><<<nchunk * 8, 256, 0, stream>>>(Cat2 + 512, offsets, edge_src, Cat2);
    gemm_mfma_kernel<0><<<ggrid, 512, 0, stream>>>(Cat2, Wcat1, bl1, nullptr, preB, 1024);
    norm_elu_kernel<0><<<nchunk, 256, 0, stream>>>(preB, nullptr, Cat2 + 512);

    // layer 3 (feat 512): final -> f32
    aggregate_kernel<512><<<nchunk * 8, 256, 0, stream>>>(Cat2 + 512, offsets, edge_src, Cat2);
    gemm_mfma_kernel<1><<<ggrid, 512, 0, stream>>>(Cat2, Wcat2, bl2, outF, nullptr, 1024);
    norm_elu_kernel<1><<<nchunk, 256, 0, stream>>>(outF, outF, nullptr);

    (void)in_sizes; (void)n_in; (void)out_size; (void)ws_size;
}

// Round 13
// 783.339 us; speedup vs baseline: 1.1429x; 1.1429x over previous
//
#include <hip/hip_runtime.h>
#include <math.h>

#define N_NODES 50000
#define M_PAD   50048   // 391 * 128
#define N_EDGES 800000
#define HID 512

typedef short bf16x8 __attribute__((ext_vector_type(8)));
typedef float f32x4  __attribute__((ext_vector_type(4)));
typedef unsigned short u16x4 __attribute__((ext_vector_type(4)));
typedef unsigned short u16x8 __attribute__((ext_vector_type(8)));

__device__ inline float b2f(unsigned short u) {
    union { unsigned int i; float f; } v; v.i = ((unsigned int)u) << 16; return v.f;
}
__device__ inline unsigned short f2b(float f) {
    union { float f; unsigned int i; } v; v.f = f;
    unsigned int r = v.i + 0x7FFFu + ((v.i >> 16) & 1u);
    return (unsigned short)(r >> 16);
}

// ---------------- CSR build ----------------

__global__ void zero_kernel(int* __restrict__ p, int n) {
    int i = blockIdx.x * blockDim.x + threadIdx.x;
    if (i < n) p[i] = 0;
}

__global__ void detect_kernel(const int* __restrict__ e, int* __restrict__ flag) {
    if (blockIdx.x == 0 && threadIdx.x == 0) {
        int is64 = 1;
        for (int i = 0; i < 16; ++i)
            if (e[2 * i + 1] != 0) is64 = 0;
        *flag = is64;
    }
}

__global__ void hist_kernel(const void* __restrict__ eidx, const int* __restrict__ flag,
                            int* __restrict__ counts) {
    int e = blockIdx.x * blockDim.x + threadIdx.x;
    if (e >= N_EDGES) return;
    int is64 = *flag;
    int d;
    if (is64) d = (int)((const long long*)eidx)[N_EDGES + e];
    else      d = ((const int*)eidx)[N_EDGES + e];
    atomicAdd(&counts[d], 1);
}

__global__ __launch_bounds__(1024) void scan_kernel(const int* __restrict__ counts,
                                                    int* __restrict__ offsets) {
    __shared__ int sums[1024];
    int t = threadIdx.x;
    const int CH = (N_NODES + 1023) / 1024;  // 49
    int lo = t * CH;
    int hi = min(lo + CH, N_NODES);
    int s = 0;
    for (int i = lo; i < hi; ++i) s += counts[i];
    sums[t] = s;
    __syncthreads();
    for (int off = 1; off < 1024; off <<= 1) {
        int v = 0;
        if (t >= off) v = sums[t - off];
        __syncthreads();
        sums[t] += v;
        __syncthreads();
    }
    int excl = (t == 0) ? 0 : sums[t - 1];
    for (int i = lo; i < hi; ++i) { offsets[i] = excl; excl += counts[i]; }
    if (t == 1023) offsets[N_NODES] = excl;
}

__global__ void fill_kernel(const void* __restrict__ eidx, const int* __restrict__ flag,
                            const int* __restrict__ offsets, int* __restrict__ cursor,
                            int* __restrict__ edge_src) {
    int e = blockIdx.x * blockDim.x + threadIdx.x;
    if (e >= N_EDGES) return;
    int is64 = *flag;
    int s, d;
    if (is64) {
        const long long* p = (const long long*)eidx;
        s = (int)p[e];
        d = (int)p[N_EDGES + e];
    } else {
        const int* p = (const int*)eidx;
        s = p[e];
        d = p[N_EDGES + e];
    }
    int pos = atomicAdd(&cursor[d], 1);
    edge_src[offsets[d] + pos] = s;
}

// ---------------- conversions ----------------

// x (f32 [N,256]) -> bf16 into feat-half of Cat1 ([M][512], cols 256..512)
__global__ __launch_bounds__(256) void xconv_kernel(const float* __restrict__ x,
                                                    unsigned short* __restrict__ cat1) {
    int id = blockIdx.x * 256 + threadIdx.x;
    if (id >= M_PAD * 64) return;
    int row = id >> 6;
    int c = (id & 63) * 4;
    float4 v = make_float4(0.f, 0.f, 0.f, 0.f);
    if (row < N_NODES) v = *(const float4*)(x + (size_t)row * 256 + c);
    ushort4 h;
    h.x = f2b(v.x); h.y = f2b(v.y); h.z = f2b(v.z); h.w = f2b(v.w);
    *(ushort4*)(cat1 + (size_t)row * 512 + 256 + c) = h;
}

// W (f32 [K,512]) -> transposed bf16 into Wcat[n][off + k], row stride ktot
__global__ __launch_bounds__(128) void wconv_kernel(const float* __restrict__ W,
                                                    unsigned short* __restrict__ T,
                                                    int K, int ktot, int off) {
    int n = blockIdx.x;  // 0..511
    for (int k = threadIdx.x; k < K; k += 128)
        T[(size_t)n * ktot + off + k] = f2b(W[(size_t)k * HID + n]);
}

// ---------------- aggregate: wave-per-node row-gather, 4 chains ----------------
// BEST MEASURED variant (R8: 116.4us; slicing family R10-R12 all worse —
// gather is fabric-bound at ~3.7 TB/s with compulsory per-XCD traffic).
// Feat width W = EPL*64, row stride 2W (halves of the concat plane).

template <int EPL>
__global__ __launch_bounds__(256) void aggregate_kernel(const unsigned short* __restrict__ Fh,
                                                        const int* __restrict__ off,
                                                        const int* __restrict__ esrc,
                                                        unsigned short* __restrict__ Ah) {
    const int STRIDE = 2 * EPL * 64;
    const int wid = threadIdx.x >> 6;
    const int lane = threadIdx.x & 63;
    const int node = blockIdx.x * 4 + wid;
    if (node >= N_NODES) return;
    const int beg = off[node], end = off[node + 1];
    const int deg = end - beg;
    const int lb = lane * EPL;
    using VecT = typename std::conditional<EPL == 8, u16x8, u16x4>::type;

    float a0[EPL], a1[EPL], a2[EPL], a3[EPL];
#pragma unroll
    for (int j = 0; j < EPL; ++j) { a0[j] = 0.f; a1[j] = 0.f; a2[j] = 0.f; a3[j] = 0.f; }

    int idxv = 0;

#define ACC(ARR, S)                                                         \
    {                                                                       \
        VecT v_ = *(const VecT*)(Fh + (size_t)(S) * STRIDE + lb);           \
        _Pragma("unroll")                                                   \
        for (int j_ = 0; j_ < EPL; ++j_) ARR[j_] += b2f(v_[j_]);            \
    }

    for (int i = 0; i < deg; i += 4) {
        const int b = i & 63;
        if (b == 0) idxv = (beg + i + lane < end) ? esrc[beg + i + lane] : 0;
        const int s0 = __shfl(idxv, b);
        const int s1 = __shfl(idxv, b + 1);
        const int s2 = __shfl(idxv, b + 2);
        const int s3 = __shfl(idxv, b + 3);
        ACC(a0, s0);
        if (i + 1 < deg) ACC(a1, s1);
        if (i + 2 < deg) ACC(a2, s2);
        if (i + 3 < deg) ACC(a3, s3);
    }
#undef ACC

    unsigned short* op = Ah + (size_t)node * STRIDE + lb;
    VecT h;
#pragma unroll
    for (int j = 0; j < EPL; ++j) h[j] = f2b(a0[j] + a1[j] + a2[j] + a3[j]);
    __builtin_nontemporal_store(h, (VecT*)op);
}

// ---------------- concat-K MFMA GEMM: 128x256 tile, 8 waves, 2-phase dbuf ----------------
// out = Acat @ Bcat^T + bias.  1D grid, bijective XCD-pair swizzle (R11: ~-14us):
// the two bn-halves of the same 128-row A panel land adjacent on the SAME XCD.

template <int FINAL>
__global__ __launch_bounds__(512, 2) void gemm_mfma_kernel(
    const unsigned short* __restrict__ A, const unsigned short* __restrict__ B,
    const float* __restrict__ bias, float* __restrict__ outF,
    unsigned short* __restrict__ pre, int K) {
    __shared__ unsigned short S[2 * 12288];  // u16 elems: 2 x (4096 A + 8192 B)
    const int T = gridDim.x;          // 782
    const int q = T >> 3, r = T & 7;
    const int xcd = blockIdx.x & 7;
    const int n0 = blockIdx.x >> 3;
    const int g = xcd * q + min(xcd, r) + n0;
    const int bm = (g >> 1) * 128;
    const int bn = (g & 1) * 256;

    const int tid = threadIdx.x;
    const int l = tid & 63;
    const int w = tid >> 6;          // 0..7
    const int wr = (w >> 2) * 64;    // 2 row-waves
    const int wc = (w & 3) * 64;     // 4 col-waves

    const int se = (tid >> 2) * 32 + (tid & 3) * 8;
    const unsigned short* gA  = A + (size_t)(bm + (tid >> 2)) * K + (tid & 3) * 8;
    const unsigned short* gB0 = B + (size_t)(bn + (tid >> 2)) * K + (tid & 3) * 8;
    const unsigned short* gB1 = B + (size_t)(bn + 128 + (tid >> 2)) * K + (tid & 3) * 8;

    f32x4 acc[4][4];
#pragma unroll
    for (int m = 0; m < 4; ++m)
#pragma unroll
        for (int nn = 0; nn < 4; ++nn) acc[m][nn] = (f32x4){0.f, 0.f, 0.f, 0.f};

    const int aoff = (wr + (l & 15)) * 32 + (l >> 4) * 8;
    const int woff = 4096 + (wc + (l & 15)) * 32 + (l >> 4) * 8;
    const int ktiles = K >> 5;

    auto STAGE = [&](int buf, int kt) {
        unsigned short* lb = &S[buf * 12288];
        __builtin_amdgcn_global_load_lds(
            (const __attribute__((address_space(1))) void*)(gA + kt * 32),
            (__attribute__((address_space(3))) void*)(lb + se), 16, 0, 0);
        __builtin_amdgcn_global_load_lds(
            (const __attribute__((address_space(1))) void*)(gB0 + kt * 32),
            (__attribute__((address_space(3))) void*)(lb + 4096 + se), 16, 0, 0);
        __builtin_amdgcn_global_load_lds(
            (const __attribute__((address_space(1))) void*)(gB1 + kt * 32),
            (__attribute__((address_space(3))) void*)(lb + 8192 + se), 16, 0, 0);
    };

    STAGE(0, 0);
    __syncthreads();

    for (int kt = 0; kt < ktiles; ++kt) {
        if (kt + 1 < ktiles) STAGE((kt + 1) & 1, kt + 1);  // prefetch next
        const int sb = (kt & 1) * 12288;

        bf16x8 af[4], wf[4];
#pragma unroll
        for (int m = 0; m < 4; ++m)
            af[m] = *(const bf16x8*)&S[sb + aoff + m * 512];
#pragma unroll
        for (int nn = 0; nn < 4; ++nn)
            wf[nn] = *(const bf16x8*)&S[sb + woff + nn * 512];
#pragma unroll
        for (int m = 0; m < 4; ++m)
#pragma unroll
            for (int nn = 0; nn < 4; ++nn)
                acc[m][nn] = __builtin_amdgcn_mfma_f32_16x16x32_bf16(af[m], wf[nn], acc[m][nn], 0, 0, 0);
        __syncthreads();
    }

    const int r0 = bm + wr + (l >> 4) * 4;
    const int c0 = bn + wc + (l & 15);
#pragma unroll
    for (int nn = 0; nn < 4; ++nn) {
        const float bv = bias[c0 + nn * 16];
#pragma unroll
        for (int m = 0; m < 4; ++m) {
#pragma unroll
            for (int j = 0; j < 4; ++j) {
                int gr = r0 + m * 16 + j;
                if (gr < N_NODES) {
                    float val = acc[m][nn][j] + bv;
                    if constexpr (FINAL)
                        outF[(size_t)gr * HID + c0 + nn * 16] = val;
                    else
                        pre[(size_t)gr * HID + c0 + nn * 16] = f2b(val);
                }
            }
        }
    }
}

// ---------------- row L2-normalize + ELU (wave-per-row) ----------------

template <int FINAL>
__global__ __launch_bounds__(256) void norm_elu_kernel(const void* __restrict__ inp,
                                                       float* __restrict__ outF,
                                                       unsigned short* __restrict__ Fh) {
    const int wid = threadIdx.x >> 6;
    const int lane = threadIdx.x & 63;
    const int row = blockIdx.x * 4 + wid;
    if (row >= N_NODES) return;
    float r[8];
    if constexpr (FINAL) {
        const float* p = (const float*)inp + (size_t)row * HID + lane * 8;
        float4 v0 = *(const float4*)p;
        float4 v1 = *(const float4*)(p + 4);
        r[0] = v0.x; r[1] = v0.y; r[2] = v0.z; r[3] = v0.w;
        r[4] = v1.x; r[5] = v1.y; r[6] = v1.z; r[7] = v1.w;
    } else {
        const unsigned short* p = (const unsigned short*)inp + (size_t)row * HID + lane * 8;
        u16x8 v = *(const u16x8*)p;
#pragma unroll
        for (int j = 0; j < 8; ++j) r[j] = b2f(v[j]);
    }
    float ss = 0.f;
#pragma unroll
    for (int j = 0; j < 8; ++j) ss += r[j] * r[j];
#pragma unroll
    for (int o = 32; o > 0; o >>= 1) ss += __shfl_xor(ss, o);
    float inv = 1.f / fmaxf(sqrtf(ss), 1e-12f);
#pragma unroll
    for (int j = 0; j < 8; ++j) {
        r[j] *= inv;
        r[j] = r[j] > 0.f ? r[j] : expm1f(r[j]);
    }
    if constexpr (FINAL) {
        float* q = outF + (size_t)row * HID + lane * 8;
        *(float4*)q = make_float4(r[0], r[1], r[2], r[3]);
        *(float4*)(q + 4) = make_float4(r[4], r[5], r[6], r[7]);
    } else {
        unsigned short* q = Fh + (size_t)row * 1024 + lane * 8;
        u16x8 h;
#pragma unroll
        for (int j = 0; j < 8; ++j) h[j] = f2b(r[j]);
        *(u16x8*)q = h;
    }
}

// ---------------- launch ----------------

extern "C" void kernel_launch(void* const* d_in, const int* in_sizes, int n_in,
                              void* d_out, int out_size, void* d_ws, size_t ws_size,
                              hipStream_t stream) {
    const float* x    = (const float*)d_in[0];
    const void*  eidx = d_in[1];
    const float* Wl0 = (const float*)d_in[2];
    const float* bl0 = (const float*)d_in[3];
    const float* Wr0 = (const float*)d_in[4];
    const float* Wl1 = (const float*)d_in[5];
    const float* bl1 = (const float*)d_in[6];
    const float* Wr1 = (const float*)d_in[7];
    const float* Wl2 = (const float*)d_in[8];
    const float* bl2 = (const float*)d_in[9];
    const float* Wr2 = (const float*)d_in[10];
    float* outF = (float*)d_out;
    unsigned short* preB = (unsigned short*)d_out;  // bf16 preact scratch (layers 1-2)

    char* ws = (char*)d_ws;
    size_t o = 0;
    auto alloc = [&](size_t bytes) { void* p = ws + o; o += (bytes + 255) & ~(size_t)255; return p; };

    // Concat activation planes: Cat1 [M][512] (agg256|feat256), Cat2 [M][1024]
    unsigned short* Cat1 = (unsigned short*)alloc((size_t)M_PAD * 512 * 2);
    unsigned short* Cat2 = (unsigned short*)alloc((size_t)M_PAD * 1024 * 2);

    unsigned short* Wcat0 = (unsigned short*)alloc(512 * 512 * 2);
    unsigned short* Wcat1 = (unsigned short*)alloc(512 * 1024 * 2);
    unsigned short* Wcat2 = (unsigned short*)alloc(512 * 1024 * 2);

    // counts and cursor MUST be one contiguous block (R2/R3 lesson: 256B alloc
    // rounding left cursor tail poisoned -> OOB writes -> GPU fault).
    int* counts   = (int*)alloc((size_t)2 * N_NODES * 4);
    int* cursor   = counts + N_NODES;
    int* offsets  = (int*)alloc((size_t)(N_NODES + 1) * 4);
    int* edge_src = (int*)alloc((size_t)N_EDGES * 4);
    int* flag     = (int*)alloc(256);

    // ---- CSR build ----
    zero_kernel<<<(2 * N_NODES + 255) / 256, 256, 0, stream>>>(counts, 2 * N_NODES);
    detect_kernel<<<1, 64, 0, stream>>>((const int*)eidx, flag);
    hist_kernel<<<(N_EDGES + 255) / 256, 256, 0, stream>>>(eidx, flag, counts);
    scan_kernel<<<1, 1024, 0, stream>>>(counts, offsets);
    fill_kernel<<<(N_EDGES + 255) / 256, 256, 0, stream>>>(eidx, flag, offsets, cursor, edge_src);

    // ---- conversions ----
    xconv_kernel<<<(M_PAD * 64 + 255) / 256, 256, 0, stream>>>(x, Cat1);
    wconv_kernel<<<512, 128, 0, stream>>>(Wl0, Wcat0, 256, 512, 0);
    wconv_kernel<<<512, 128, 0, stream>>>(Wr0, Wcat0, 256, 512, 256);
    wconv_kernel<<<512, 128, 0, stream>>>(Wl1, Wcat1, 512, 1024, 0);
    wconv_kernel<<<512, 128, 0, stream>>>(Wr1, Wcat1, 512, 1024, 512);
    wconv_kernel<<<512, 128, 0, stream>>>(Wl2, Wcat2, 512, 1024, 0);
    wconv_kernel<<<512, 128, 0, stream>>>(Wr2, Wcat2, 512, 1024, 512);

    const int ggrid = 2 * (M_PAD / 128);   // 782, 1D (swizzle computes bm/bn)
    const int nchunk = (N_NODES + 3) / 4;  // 4 nodes (waves) per 256-block

    // layer 1 (feat 256): Cat1 = agg|x, K=512
    aggregate_kernel<4><<<nchunk, 256, 0, stream>>>(Cat1 + 256, offsets, edge_src, Cat1);
    gemm_mfma_kernel<0><<<ggrid, 512, 0, stream>>>(Cat1, Wcat0, bl0, nullptr, preB, 512);
    norm_elu_kernel<0><<<nchunk, 256, 0, stream>>>(preB, nullptr, Cat2 + 512);

    // layer 2 (feat 512): Cat2 = agg|feat, K=1024
    aggregate_kernel<8><<<nchunk, 256, 0, stream>>>(Cat2 + 512, offsets, edge_src, Cat2);
    gemm_mfma_kernel<0><<<ggrid, 512, 0, stream>>>(Cat2, Wcat1, bl1, nullptr, preB, 1024);
    norm_elu_kernel<0><<<nchunk, 256, 0, stream>>>(preB, nullptr, Cat2 + 512);

    // layer 3 (feat 512): final -> f32
    aggregate_kernel<8><<<nchunk, 256, 0, stream>>>(Cat2 + 512, offsets, edge_src, Cat2);
    gemm_mfma_kernel<1><<<ggrid, 512, 0, stream>>>(Cat2, Wcat2, bl2, outF, nullptr, 1024);
    norm_elu_kernel<1><<<nchunk, 256, 0, stream>>>(outF, outF, nullptr);

    (void)in_sizes; (void)n_in; (void)out_size; (void)ws_size;
}